// Round 1
// baseline (134.500 us; speedup 1.0000x reference)
//
#include <hip/hip_runtime.h>

// FeatureFusionModule: fused = concat(shared, special, axis=1) [65536, 2048]
//   fusion_features = fused.reshape(16384, 4, 2048).sum(axis=1)   -> [16384, 2048] f32
//   fusion_pids     = pids[::4]                                   -> [16384] (written as float)
// d_out layout: 16384*2048 floats of features, then 16384 floats of pids.

using f4 = __attribute__((ext_vector_type(4))) float;

// Problem-fixed geometry (derived from setup_inputs: bs=65536, d=1024, views=4).
// D4      = d/4 = 256 float4 per input row
// OUTROW4 = 2*d/4 = 512 float4 per output row

__global__ __launch_bounds__(256) void feature_fusion_kernel(
    const f4* __restrict__ shf,      // [bs][256] float4
    const f4* __restrict__ spf,      // [bs][256] float4
    const int* __restrict__ pids,    // [bs]
    f4* __restrict__ out,            // [chunk][512] float4
    float* __restrict__ out_pids,    // [chunk]
    int total_f4)                    // chunk * 512
{
    const int stride = gridDim.x * blockDim.x;
    for (int j = blockIdx.x * blockDim.x + threadIdx.x; j < total_f4; j += stride) {
        const int i = j >> 9;          // output row (group of 4 input rows)
        const int c = j & 511;         // float4 column within output row
        // input rows 4*i .. 4*i+3; row stride = 256 float4
        const size_t base = (size_t)i * 1024 + (size_t)(c & 255);
        const f4* __restrict__ src = (c < 256) ? shf : spf;  // wave-uniform branch
        f4 a = src[base];
        f4 b = src[base + 256];
        f4 d = src[base + 512];
        f4 e = src[base + 768];
        out[j] = (a + b) + (d + e);
        if (c == 0) {
            out_pids[i] = (float)pids[(size_t)i * 4];
        }
    }
}

extern "C" void kernel_launch(void* const* d_in, const int* in_sizes, int n_in,
                              void* d_out, int out_size, void* d_ws, size_t ws_size,
                              hipStream_t stream) {
    const f4*  shf  = (const f4*)d_in[0];
    const f4*  spf  = (const f4*)d_in[1];
    const int* pids = (const int*)d_in[2];

    const int bs    = in_sizes[2];          // 65536
    const int d     = in_sizes[0] / bs;     // 1024
    const int chunk = bs / 4;               // 16384
    const int total_f4 = chunk * (2 * d / 4);  // 16384 * 512 = 8388608

    float* out      = (float*)d_out;
    float* out_pids = out + (size_t)chunk * (size_t)(2 * d);  // after features

    const int block = 256;
    const int grid  = 2048;   // grid-stride; ~8 blocks/CU worth of waves
    feature_fusion_kernel<<<grid, block, 0, stream>>>(shf, spf, pids,
                                                      (f4*)out, out_pids, total_f4);
}

// Round 2
// 127.257 us; speedup vs baseline: 1.0569x; 1.0569x over previous
//
#include <hip/hip_runtime.h>

// FeatureFusionModule: fused = concat(shared, special, axis=1) [65536, 2048]
//   fusion_features = fused.reshape(16384, 4, 2048).sum(axis=1)   -> [16384, 2048] f32
//   fusion_pids     = pids[::4]                                   -> [16384] (written as float)
// d_out layout: 16384*2048 floats of features, then 16384 floats of pids.
//
// R1: 134.5 us @ ~5.0 TB/s effective (79% of 6.3 TB/s achievable).
// R2 change: nontemporal stores (output has zero reuse; avoid L2/L3
//            write-allocate pollution that evicts input lines).

using f4 = __attribute__((ext_vector_type(4))) float;

__global__ __launch_bounds__(256) void feature_fusion_kernel(
    const f4* __restrict__ shf,      // [bs][256] float4
    const f4* __restrict__ spf,      // [bs][256] float4
    const int* __restrict__ pids,    // [bs]
    f4* __restrict__ out,            // [chunk][512] float4
    float* __restrict__ out_pids,    // [chunk]
    int total_f4)                    // chunk * 512
{
    const int stride = gridDim.x * blockDim.x;
    for (int j = blockIdx.x * blockDim.x + threadIdx.x; j < total_f4; j += stride) {
        const int i = j >> 9;          // output row (group of 4 input rows)
        const int c = j & 511;         // float4 column within output row
        // input rows 4*i .. 4*i+3; row stride = 256 float4
        const size_t base = (size_t)i * 1024 + (size_t)(c & 255);
        const f4* __restrict__ src = (c < 256) ? shf : spf;  // wave-uniform branch
        f4 a = src[base];
        f4 b = src[base + 256];
        f4 d = src[base + 512];
        f4 e = src[base + 768];
        f4 r = (a + b) + (d + e);
        __builtin_nontemporal_store(r, &out[j]);
        if (c == 0) {
            float p = (float)pids[(size_t)i * 4];
            __builtin_nontemporal_store(p, &out_pids[i]);
        }
    }
}

extern "C" void kernel_launch(void* const* d_in, const int* in_sizes, int n_in,
                              void* d_out, int out_size, void* d_ws, size_t ws_size,
                              hipStream_t stream) {
    const f4*  shf  = (const f4*)d_in[0];
    const f4*  spf  = (const f4*)d_in[1];
    const int* pids = (const int*)d_in[2];

    const int bs    = in_sizes[2];          // 65536
    const int d     = in_sizes[0] / bs;     // 1024
    const int chunk = bs / 4;               // 16384
    const int total_f4 = chunk * (2 * d / 4);  // 16384 * 512 = 8388608

    float* out      = (float*)d_out;
    float* out_pids = out + (size_t)chunk * (size_t)(2 * d);  // after features

    const int block = 256;
    const int grid  = 2048;   // grid-stride; 8 blocks/CU -> 32 waves/CU
    feature_fusion_kernel<<<grid, block, 0, stream>>>(shf, spf, pids,
                                                      (f4*)out, out_pids, total_f4);
}

// Round 3
// 119.011 us; speedup vs baseline: 1.1302x; 1.0693x over previous
//
#include <hip/hip_runtime.h>

// FeatureFusionModule: fused = concat(shared, special, axis=1) [65536, 2048]
//   fusion_features = fused.reshape(16384, 4, 2048).sum(axis=1)   -> [16384, 2048] f32
//   fusion_pids     = pids[::4]                                   -> [16384] (written as float)
// d_out layout: 16384*2048 floats of features, then 16384 floats of pids.
//
// R1: 134.5 us, cached loads/stores. ~5.0 TB/s effective.
// R2: 127.3 us, NT stores (+5.4%). FETCH=269MB (L3 retains ~half of inputs
//     across replays), WRITE=134MB. Effective fabric BW 5.27 TB/s = 84% of copy ceiling.
// R3 experiment: NT loads too -> pure HBM stream, no L3 allocate. Tests whether
//     the limit is HBM (win -> ~107us) or the L2<->fabric path (neutral/worse -> revert).

using f4 = __attribute__((ext_vector_type(4))) float;

__global__ __launch_bounds__(256) void feature_fusion_kernel(
    const f4* __restrict__ shf,      // [bs][256] float4
    const f4* __restrict__ spf,      // [bs][256] float4
    const int* __restrict__ pids,    // [bs]
    f4* __restrict__ out,            // [chunk][512] float4
    float* __restrict__ out_pids,    // [chunk]
    int total_f4)                    // chunk * 512
{
    const int stride = gridDim.x * blockDim.x;
    for (int j = blockIdx.x * blockDim.x + threadIdx.x; j < total_f4; j += stride) {
        const int i = j >> 9;          // output row (group of 4 input rows)
        const int c = j & 511;         // float4 column within output row
        // input rows 4*i .. 4*i+3; row stride = 256 float4
        const size_t base = (size_t)i * 1024 + (size_t)(c & 255);
        const f4* __restrict__ src = (c < 256) ? shf : spf;  // wave-uniform branch
        f4 a = __builtin_nontemporal_load(&src[base]);
        f4 b = __builtin_nontemporal_load(&src[base + 256]);
        f4 d = __builtin_nontemporal_load(&src[base + 512]);
        f4 e = __builtin_nontemporal_load(&src[base + 768]);
        f4 r = (a + b) + (d + e);
        __builtin_nontemporal_store(r, &out[j]);
        if (c == 0) {
            float p = (float)pids[(size_t)i * 4];
            __builtin_nontemporal_store(p, &out_pids[i]);
        }
    }
}

extern "C" void kernel_launch(void* const* d_in, const int* in_sizes, int n_in,
                              void* d_out, int out_size, void* d_ws, size_t ws_size,
                              hipStream_t stream) {
    const f4*  shf  = (const f4*)d_in[0];
    const f4*  spf  = (const f4*)d_in[1];
    const int* pids = (const int*)d_in[2];

    const int bs    = in_sizes[2];          // 65536
    const int d     = in_sizes[0] / bs;     // 1024
    const int chunk = bs / 4;               // 16384
    const int total_f4 = chunk * (2 * d / 4);  // 16384 * 512 = 8388608

    float* out      = (float*)d_out;
    float* out_pids = out + (size_t)chunk * (size_t)(2 * d);  // after features

    const int block = 256;
    const int grid  = 2048;   // grid-stride; 8 blocks/CU -> 32 waves/CU
    feature_fusion_kernel<<<grid, block, 0, stream>>>(shf, spf, pids,
                                                      (f4*)out, out_pids, total_f4);
}

// Round 4
// 113.990 us; speedup vs baseline: 1.1799x; 1.0440x over previous
//
#include <hip/hip_runtime.h>

// FeatureFusionModule: fused = concat(shared, special, axis=1) [65536, 2048]
//   fusion_features = fused.reshape(16384, 4, 2048).sum(axis=1)   -> [16384, 2048] f32
//   fusion_pids     = pids[::4]                                   -> [16384] (written as float)
// d_out layout: 16384*2048 floats of features, then 16384 floats of pids.
//
// R1: 134.5 us cached.  R2: 127.3 us NT stores.  R3: 119.0 us all-NT (5.67 TB/s).
// R4: exact mapping, 4 outputs/thread, all 16 NT loads issued before any use
//     (deep MLP). Tile: block covers 1024 consecutive f4; thread t handles
//     j = J0 + t + 256*k, k=0..3 -> every load instruction perfectly coalesced.

using f4 = __attribute__((ext_vector_type(4))) float;

__global__ __launch_bounds__(256) void feature_fusion_kernel(
    const f4* __restrict__ shf,      // [bs][256] float4
    const f4* __restrict__ spf,      // [bs][256] float4
    const int* __restrict__ pids,    // [bs]
    f4* __restrict__ out,            // [chunk][512] float4
    float* __restrict__ out_pids)    // [chunk]
{
    const int j0 = blockIdx.x * 1024 + threadIdx.x;  // block tile: 1024 f4

    f4 v[4][4];                      // [k-group][input row]
#pragma unroll
    for (int k = 0; k < 4; ++k) {
        const int j = j0 + (k << 8);
        const int i = j >> 9;          // output row
        const int c = j & 511;         // f4 column in output row
        const f4* __restrict__ src = (c < 256) ? shf : spf;  // wave-uniform
        const size_t base = (size_t)i * 1024 + (size_t)(c & 255);
        v[k][0] = __builtin_nontemporal_load(&src[base]);
        v[k][1] = __builtin_nontemporal_load(&src[base + 256]);
        v[k][2] = __builtin_nontemporal_load(&src[base + 512]);
        v[k][3] = __builtin_nontemporal_load(&src[base + 768]);
    }
#pragma unroll
    for (int k = 0; k < 4; ++k) {
        const int j = j0 + (k << 8);
        f4 r = (v[k][0] + v[k][1]) + (v[k][2] + v[k][3]);
        __builtin_nontemporal_store(r, &out[j]);
        if ((j & 511) == 0) {
            const int i = j >> 9;
            float p = (float)pids[(size_t)i * 4];
            __builtin_nontemporal_store(p, &out_pids[i]);
        }
    }
}

extern "C" void kernel_launch(void* const* d_in, const int* in_sizes, int n_in,
                              void* d_out, int out_size, void* d_ws, size_t ws_size,
                              hipStream_t stream) {
    const f4*  shf  = (const f4*)d_in[0];
    const f4*  spf  = (const f4*)d_in[1];
    const int* pids = (const int*)d_in[2];

    const int bs    = in_sizes[2];          // 65536
    const int d     = in_sizes[0] / bs;     // 1024
    const int chunk = bs / 4;               // 16384
    const int total_f4 = chunk * (2 * d / 4);  // 8388608

    float* out      = (float*)d_out;
    float* out_pids = out + (size_t)chunk * (size_t)(2 * d);  // after features

    const int block = 256;
    const int grid  = total_f4 / 1024;      // 8192 blocks, exact (no tail)
    feature_fusion_kernel<<<grid, block, 0, stream>>>(shf, spf, pids,
                                                      (f4*)out, out_pids);
}